// Round 6
// baseline (226.911 us; speedup 1.0000x reference)
//
#include <hip/hip_runtime.h>

// SpatialTransformer: trilinear warp of vol [B,X,Y,Z,1] by dense flow [B,X,Y,Z,3].
// B=2, X=Y=Z=160, fp32 everywhere.
//
// vs round-1 (103 us, 2.0 TB/s, FETCH 171.5 MB):
//  - XCD-aware bijective block swizzle: each XCD gets a contiguous 1/8 slab
//    -> per-XCD vol working set ~2 MB, fits the 4 MB per-XCD L2.
//  - Nontemporal flow loads + out stores: 130 MB of streaming traffic no
//    longer evicts vol from L2.
//  - Flow staged through LDS via coalesced 16B loads (was stride-12B
//    dword loads spanning 12 lines/wave-instr).
//  - fix: __builtin_nontemporal_load needs a clang ext_vector type, not
//    HIP's float4 class -> use f32x4 typedef.

typedef float f32x4 __attribute__((ext_vector_type(4)));

#define DIM 160
#define DD  (DIM * DIM)
#define DDD (DIM * DIM * DIM)
#define BATCH 2
#define TOTAL (BATCH * DDD)
#define BLK 256
#define NBLK (TOTAL / BLK)      // 32000, divisible by 8
#define NXCD 8
#define CHUNK (NBLK / NXCD)     // 4000

__global__ __launch_bounds__(256) void st_warp_kernel(
    const float* __restrict__ vol,
    const float* __restrict__ flow,
    float* __restrict__ out)
{
    __shared__ float sflow[BLK * 3];   // 3 KiB

    int tid = threadIdx.x;
    int bid = blockIdx.x;
    // bijective XCD swizzle: blocks landing on XCD k (k = bid % 8) process the
    // contiguous chunk [k*CHUNK, (k+1)*CHUNK)
    int swz  = (bid & 7) * CHUNK + (bid >> 3);
    int base = swz * BLK;              // first output voxel of this block

    // stage this block's flow (768 floats = 192 x 16B) into LDS with
    // coalesced nontemporal loads; base*3*4 = swz*3072 -> 16B-aligned
    const f32x4* fsrc = (const f32x4*)(flow + (size_t)base * 3);
    if (tid < 192) {
        f32x4 v = __builtin_nontemporal_load(&fsrc[tid]);
        ((f32x4*)sflow)[tid] = v;
    }
    __syncthreads();

    int idx = base + tid;

    // decompose idx -> (b, x, y, z); z fastest (matches [B,X,Y,Z] row-major)
    int b   = idx / DDD;
    int rem = idx - b * DDD;
    int x   = rem / DD;
    int r2  = rem - x * DD;
    int y   = r2 / DIM;
    int z   = r2 - y * DIM;

    // LDS read at dword stride 3: gcd(3,32)=1 -> 2-way bank aliasing (free)
    float fx = sflow[tid * 3 + 0];
    float fy = sflow[tid * 3 + 1];
    float fz = sflow[tid * 3 + 2];

    const float maxf = (float)(DIM - 1);

    // absolute sample location, clipped (matches jnp.clip(loc, 0, d-1))
    float lx = fminf(fmaxf((float)x + fx, 0.0f), maxf);
    float ly = fminf(fmaxf((float)y + fy, 0.0f), maxf);
    float lz = fminf(fmaxf((float)z + fz, 0.0f), maxf);

    // floor -> corner 0
    int x0 = (int)floorf(lx);
    int y0 = (int)floorf(ly);
    int z0 = (int)floorf(lz);
    x0 = min(max(x0, 0), DIM - 1);
    y0 = min(max(y0, 0), DIM - 1);
    z0 = min(max(z0, 0), DIM - 1);

    int x1 = min(x0 + 1, DIM - 1);
    int y1 = min(y0 + 1, DIM - 1);
    int z1 = min(z0 + 1, DIM - 1);

    // voxelmorph weights: w_lo = float(loc1i) - clipped_loc ; w_hi = 1 - w_lo
    float wx0 = (float)x1 - lx;  float wx1 = 1.0f - wx0;
    float wy0 = (float)y1 - ly;  float wy1 = 1.0f - wy0;
    float wz0 = (float)z1 - lz;  float wz1 = 1.0f - wz0;

    const float* vb = vol + (size_t)b * DDD;

    int bx0 = x0 * DD, bx1 = x1 * DD;
    int by0 = y0 * DIM, by1 = y1 * DIM;

    // 8 corner gathers; z-neighbors adjacent in memory, and after the XCD
    // swizzle the working set (~2 MB slab) stays resident in the per-XCD L2
    float v000 = vb[bx0 + by0 + z0];
    float v100 = vb[bx1 + by0 + z0];
    float v010 = vb[bx0 + by1 + z0];
    float v110 = vb[bx1 + by1 + z0];
    float v001 = vb[bx0 + by0 + z1];
    float v101 = vb[bx1 + by0 + z1];
    float v011 = vb[bx0 + by1 + z1];
    float v111 = vb[bx1 + by1 + z1];

    float acc;
    acc  = v000 * (wx0 * wy0 * wz0);
    acc += v100 * (wx1 * wy0 * wz0);
    acc += v010 * (wx0 * wy1 * wz0);
    acc += v110 * (wx1 * wy1 * wz0);
    acc += v001 * (wx0 * wy0 * wz1);
    acc += v101 * (wx1 * wy0 * wz1);
    acc += v011 * (wx0 * wy1 * wz1);
    acc += v111 * (wx1 * wy1 * wz1);

    __builtin_nontemporal_store(acc, &out[idx]);
}

extern "C" void kernel_launch(void* const* d_in, const int* in_sizes, int n_in,
                              void* d_out, int out_size, void* d_ws, size_t ws_size,
                              hipStream_t stream)
{
    const float* vol  = (const float*)d_in[0];
    const float* flow = (const float*)d_in[1];
    float* out = (float*)d_out;

    st_warp_kernel<<<NBLK, BLK, 0, stream>>>(vol, flow, out);
}

// Round 7
// 212.484 us; speedup vs baseline: 1.0679x; 1.0679x over previous
//
#include <hip/hip_runtime.h>

// SpatialTransformer: trilinear warp of vol [B,X,Y,Z,1] by dense flow [B,X,Y,Z,3].
// B=2, X=Y=Z=160, fp32 everywhere.
//
// Round-7 change vs round-6 (91 us, 1.1 TB/s, VALU 22%, L1-transaction bound):
//  - z-corner PAIR loads: v(x,y,z0) and v(x,y,z1) are adjacent dwords ->
//    one unaligned 8B load each for the 4 (x,y) rows. Halves gather
//    instructions (8 -> 4 per voxel) and L1 line transactions.
//    Edge z0=159 handled by loading at zb=min(z0,158): there wz0==0.0
//    exactly, so pair.x contributes 0 bitwise, matching the reference.
//  - keeps: XCD bijective swizzle, nontemporal flow/out, LDS flow staging.

typedef float f32x4 __attribute__((ext_vector_type(4)));
typedef float f32x2 __attribute__((ext_vector_type(2), aligned(4)));  // 4B-aligned 8B load

#define DIM 160
#define DD  (DIM * DIM)
#define DDD (DIM * DIM * DIM)
#define BATCH 2
#define TOTAL (BATCH * DDD)
#define BLK 256
#define NBLK (TOTAL / BLK)      // 32000, divisible by 8
#define NXCD 8
#define CHUNK (NBLK / NXCD)     // 4000

__global__ __launch_bounds__(256) void st_warp_kernel(
    const float* __restrict__ vol,
    const float* __restrict__ flow,
    float* __restrict__ out)
{
    __shared__ float sflow[BLK * 3];   // 3 KiB

    int tid = threadIdx.x;
    int bid = blockIdx.x;
    // bijective XCD swizzle: blocks landing on XCD k (k = bid % 8) process the
    // contiguous chunk [k*CHUNK, (k+1)*CHUNK)
    int swz  = (bid & 7) * CHUNK + (bid >> 3);
    int base = swz * BLK;              // first output voxel of this block

    // stage this block's flow (768 floats = 192 x 16B) into LDS with
    // coalesced nontemporal loads; base*3*4 = swz*3072 -> 16B-aligned
    const f32x4* fsrc = (const f32x4*)(flow + (size_t)base * 3);
    if (tid < 192) {
        f32x4 v = __builtin_nontemporal_load(&fsrc[tid]);
        ((f32x4*)sflow)[tid] = v;
    }
    __syncthreads();

    int idx = base + tid;

    // decompose idx -> (b, x, y, z); z fastest (matches [B,X,Y,Z] row-major)
    int b   = idx / DDD;
    int rem = idx - b * DDD;
    int x   = rem / DD;
    int r2  = rem - x * DD;
    int y   = r2 / DIM;
    int z   = r2 - y * DIM;

    // LDS read at dword stride 3: gcd(3,32)=1 -> 2-way bank aliasing (free)
    float fx = sflow[tid * 3 + 0];
    float fy = sflow[tid * 3 + 1];
    float fz = sflow[tid * 3 + 2];

    const float maxf = (float)(DIM - 1);

    // absolute sample location, clipped (matches jnp.clip(loc, 0, d-1))
    float lx = fminf(fmaxf((float)x + fx, 0.0f), maxf);
    float ly = fminf(fmaxf((float)y + fy, 0.0f), maxf);
    float lz = fminf(fmaxf((float)z + fz, 0.0f), maxf);

    // floor -> corner 0
    int x0 = (int)floorf(lx);
    int y0 = (int)floorf(ly);
    int z0 = (int)floorf(lz);
    x0 = min(max(x0, 0), DIM - 1);
    y0 = min(max(y0, 0), DIM - 1);
    z0 = min(max(z0, 0), DIM - 1);

    int x1 = min(x0 + 1, DIM - 1);
    int y1 = min(y0 + 1, DIM - 1);
    int z1 = min(z0 + 1, DIM - 1);

    // voxelmorph weights: w_lo = float(loc1i) - clipped_loc ; w_hi = 1 - w_lo
    float wx0 = (float)x1 - lx;  float wx1 = 1.0f - wx0;
    float wy0 = (float)y1 - ly;  float wy1 = 1.0f - wy0;
    float wz0 = (float)z1 - lz;  float wz1 = 1.0f - wz0;

    const float* vb = vol + (size_t)b * DDD;

    int bx0 = x0 * DD, bx1 = x1 * DD;
    int by0 = y0 * DIM, by1 = y1 * DIM;

    // paired z gathers: 4 x 8B unaligned loads instead of 8 x 4B.
    // zb=min(z0,158): when z0==159, wz0==0.0 exactly (lz==159.0), so the
    // stale .x element contributes 0 and .y==v(159) carries weight 1.
    int zb = min(z0, DIM - 2);
    f32x2 p00 = *(const f32x2*)(vb + bx0 + by0 + zb);
    f32x2 p10 = *(const f32x2*)(vb + bx1 + by0 + zb);
    f32x2 p01 = *(const f32x2*)(vb + bx0 + by1 + zb);
    f32x2 p11 = *(const f32x2*)(vb + bx1 + by1 + zb);

    float v000 = p00.x, v001 = p00.y;
    float v100 = p10.x, v101 = p10.y;
    float v010 = p01.x, v011 = p01.y;
    float v110 = p11.x, v111 = p11.y;

    // accumulate in the exact reference corner order (c = 0..7)
    float acc;
    acc  = v000 * (wx0 * wy0 * wz0);
    acc += v100 * (wx1 * wy0 * wz0);
    acc += v010 * (wx0 * wy1 * wz0);
    acc += v110 * (wx1 * wy1 * wz0);
    acc += v001 * (wx0 * wy0 * wz1);
    acc += v101 * (wx1 * wy0 * wz1);
    acc += v011 * (wx0 * wy1 * wz1);
    acc += v111 * (wx1 * wy1 * wz1);

    __builtin_nontemporal_store(acc, &out[idx]);
}

extern "C" void kernel_launch(void* const* d_in, const int* in_sizes, int n_in,
                              void* d_out, int out_size, void* d_ws, size_t ws_size,
                              hipStream_t stream)
{
    const float* vol  = (const float*)d_in[0];
    const float* flow = (const float*)d_in[1];
    float* out = (float*)d_out;

    st_warp_kernel<<<NBLK, BLK, 0, stream>>>(vol, flow, out);
}

// Round 10
// 202.663 us; speedup vs baseline: 1.1196x; 1.0485x over previous
//
#include <hip/hip_runtime.h>

// SpatialTransformer: trilinear warp of vol [B,X,Y,Z,1] by dense flow [B,X,Y,Z,3].
// B=2, X=Y=Z=160, fp32.
//
// Round-8 vs round-7 (78 us, L1-transaction bound):
//  - wave = compact 4x4x4 voxel tile (block = 4x4x16). Gaussian flow jitter
//    (+-2 voxels) scatters a z-line wave over ~20 rows x z-spread lanes
//    (~70 lines/gather); a cubic wave tile spans ~7x7 rows with 8-z-wide
//    contiguous segments -> ~30 lines/gather. ~2x fewer L1 transactions.
//  - flow staged to LDS per-row (16 rows x 12 float4, coalesced, nontemporal)
//  - out staged through LDS, written as 16 z-contiguous 64B row segments
//  - keeps: z-pair 8B gathers, bijective XCD chunk swizzle, nontemporal hints.

typedef float f32x4 __attribute__((ext_vector_type(4)));
typedef float f32x2 __attribute__((ext_vector_type(2), aligned(4)));

#define DIM 160
#define DD  (DIM * DIM)
#define DDD (DIM * DIM * DIM)
#define BATCH 2
#define BLK 256
#define NBX 40
#define NBY 40
#define NBZ 10
#define NBLK (BATCH * NBX * NBY * NBZ)   // 32000, divisible by 8
#define CHUNK (NBLK / 8)                  // 4000

// sflow row stride 52 floats (12 float4 data + 1 pad) -> row*52 mod 32 has
// period 8 in banks; same-bank rows are 2-way (free). sout read is <=4-way.
#define FROW 52

__global__ __launch_bounds__(256) void st_warp_kernel(
    const float* __restrict__ vol,
    const float* __restrict__ flow,
    float* __restrict__ out)
{
    __shared__ float sflow[16 * FROW];   // 3.25 KiB
    __shared__ float sout[BLK];          // 1 KiB

    int tid = threadIdx.x;
    int bid = blockIdx.x;
    // bijective XCD swizzle: XCD k gets contiguous chunk [k*CHUNK,(k+1)*CHUNK)
    int swz = (bid & 7) * CHUNK + (bid >> 3);

    // decode tile id: zb fastest, then yb, xb, bb  (consecutive swz -> z-adjacent)
    int bb = swz / (NBX * NBY * NBZ);
    int r  = swz - bb * (NBX * NBY * NBZ);
    int xb = r / (NBY * NBZ);
    int r2 = r - xb * (NBY * NBZ);
    int yb = r2 / NBZ;
    int zb = r2 - yb * NBZ;

    int x0b = xb * 4, y0b = yb * 4, z0b = zb * 16;

    // ---- stage flow: 16 rows x (16 z * 3) floats = 12 float4 per row ----
    if (tid < 192) {
        int rr = tid / 12;            // row 0..15
        int q  = tid - rr * 12;       // float4 within row
        int xr = x0b + (rr >> 2);
        int yr = y0b + (rr & 3);
        const f32x4* src = (const f32x4*)(flow +
            ((size_t)((bb * DIM + xr) * DIM + yr) * DIM + z0b) * 3);
        f32x4 v = __builtin_nontemporal_load(&src[q]);
        *(f32x4*)&sflow[rr * FROW + q * 4] = v;
    }
    __syncthreads();

    // ---- thread -> voxel inside 4x4x16 tile; each wave owns a 4x4x4 cube ----
    int lx  = (tid >> 4) & 3;
    int ly  = (tid >> 2) & 3;
    int lz  = ((tid >> 6) << 2) | (tid & 3);   // 0..15
    int row = (lx << 2) | ly;                  // 0..15

    float fx = sflow[row * FROW + lz * 3 + 0];
    float fy = sflow[row * FROW + lz * 3 + 1];
    float fz = sflow[row * FROW + lz * 3 + 2];

    int x = x0b + lx, y = y0b + ly, z = z0b + lz;

    const float maxf = (float)(DIM - 1);

    float lxf = fminf(fmaxf((float)x + fx, 0.0f), maxf);
    float lyf = fminf(fmaxf((float)y + fy, 0.0f), maxf);
    float lzf = fminf(fmaxf((float)z + fz, 0.0f), maxf);

    int x0 = (int)floorf(lxf);
    int y0 = (int)floorf(lyf);
    int z0 = (int)floorf(lzf);
    x0 = min(max(x0, 0), DIM - 1);
    y0 = min(max(y0, 0), DIM - 1);
    z0 = min(max(z0, 0), DIM - 1);

    int x1 = min(x0 + 1, DIM - 1);
    int y1 = min(y0 + 1, DIM - 1);
    int z1 = min(z0 + 1, DIM - 1);

    // voxelmorph weights
    float wx0 = (float)x1 - lxf;  float wx1 = 1.0f - wx0;
    float wy0 = (float)y1 - lyf;  float wy1 = 1.0f - wy0;
    float wz0 = (float)z1 - lzf;  float wz1 = 1.0f - wz0;

    const float* vb = vol + (size_t)bb * DDD;
    int bx0 = x0 * DD, bx1 = x1 * DD;
    int by0 = y0 * DIM, by1 = y1 * DIM;

    // paired z gathers (z0,z1 adjacent dwords). zb=min(z0,158): at z0==159
    // wz0==0.0 exactly, so the stale low element contributes exactly 0.
    int zp = min(z0, DIM - 2);
    f32x2 p00 = *(const f32x2*)(vb + bx0 + by0 + zp);
    f32x2 p10 = *(const f32x2*)(vb + bx1 + by0 + zp);
    f32x2 p01 = *(const f32x2*)(vb + bx0 + by1 + zp);
    f32x2 p11 = *(const f32x2*)(vb + bx1 + by1 + zp);

    // accumulate in exact reference corner order
    float acc;
    acc  = p00.x * (wx0 * wy0 * wz0);
    acc += p10.x * (wx1 * wy0 * wz0);
    acc += p01.x * (wx0 * wy1 * wz0);
    acc += p11.x * (wx1 * wy1 * wz0);
    acc += p00.y * (wx0 * wy0 * wz1);
    acc += p10.y * (wx1 * wy0 * wz1);
    acc += p01.y * (wx0 * wy1 * wz1);
    acc += p11.y * (wx1 * wy1 * wz1);

    // ---- stage out and store coalesced (16 rows x 64B z-segments) ----
    sout[tid] = acc;
    __syncthreads();

    int ro = tid >> 4;     // row 0..15
    int zo = tid & 15;     // z within tile
    // producer thread of voxel (ro, zo): wave zo>>2, lx=ro>>2, ly=ro&3, dz=zo&3
    int tsrc = ((zo >> 2) << 6) | ((ro >> 2) << 4) | ((ro & 3) << 2) | (zo & 3);
    int xs = x0b + (ro >> 2);
    int ys = y0b + (ro & 3);
    float v = sout[tsrc];
    __builtin_nontemporal_store(v,
        &out[(size_t)((bb * DIM + xs) * DIM + ys) * DIM + z0b + zo]);
}

extern "C" void kernel_launch(void* const* d_in, const int* in_sizes, int n_in,
                              void* d_out, int out_size, void* d_ws, size_t ws_size,
                              hipStream_t stream)
{
    const float* vol  = (const float*)d_in[0];
    const float* flow = (const float*)d_in[1];
    float* out = (float*)d_out;

    st_warp_kernel<<<NBLK, BLK, 0, stream>>>(vol, flow, out);
}

// Round 11
// 196.577 us; speedup vs baseline: 1.1543x; 1.0310x over previous
//
#include <hip/hip_runtime.h>

// SpatialTransformer: trilinear warp of vol [B,X,Y,Z,1] by dense flow [B,X,Y,Z,3].
// B=2, X=Y=Z=160, fp32.
//
// Round-11 vs round-10 (69 us, VALU 36%, co-limited VALU + L1-gather + latency):
//  - 2 voxels per thread (block tile 4x4x32): 8 independent gathers in flight
//    per thread, flow staging + decode + store amortized.
//  - VALU trim: no redundant clamps (floor of clipped value is in-range),
//    trunc instead of floorf, delta-based corner addresses (2 u24 muls),
//    factored FMA interpolation tree (14 ops vs 20; fp32 reassociation,
//    error ~1e-6 << 7.5e-2 threshold).
//  - out written as f32x2 (128B z-segments per row), staged via padded LDS.
//  - keeps: wave = 4x4x4 cube per half-tile, z-pair 8B gathers, bijective
//    XCD chunk swizzle, nontemporal flow/out, L1-cached vol gathers.

typedef float f32x4 __attribute__((ext_vector_type(4)));
typedef float f32x2u __attribute__((ext_vector_type(2), aligned(4)));  // vol pairs (4B-aligned)
typedef float f32x2 __attribute__((ext_vector_type(2)));               // 8B-aligned

#define DIM 160
#define DD  (DIM * DIM)
#define DDD (DIM * DIM * DIM)
#define BLK 256
#define NBX 40
#define NBY 40
#define NBZ 5
#define TPB (NBX * NBY * NBZ)     // 8000 tiles per batch
#define NBLK (2 * TPB)            // 16000, divisible by 8
#define CHUNK (NBLK / 8)          // 2000

#define FROW 100   // 96 data floats + 4 pad: row*100 mod 32 = row*4 -> 2-way (free)
#define SOROW 34   // even stride: 8B-aligned f32x2, ~2-4 way on few LDS ops

__global__ __launch_bounds__(256) void st_warp_kernel(
    const float* __restrict__ vol,
    const float* __restrict__ flow,
    float* __restrict__ out)
{
    __shared__ float sflow[16 * FROW];   // 6.4 KiB
    __shared__ float sout[16 * SOROW];   // 2.2 KiB

    int tid = threadIdx.x;
    int bid = blockIdx.x;
    // bijective XCD swizzle: XCD k gets contiguous chunk [k*CHUNK,(k+1)*CHUNK)
    int swz = (bid & 7) * CHUNK + (bid >> 3);

    // decode tile id: zb fastest
    int bb = swz / TPB;
    int r  = swz - bb * TPB;
    int xb = r / (NBY * NBZ);
    int r2 = r - xb * (NBY * NBZ);
    int yb = r2 / NBZ;
    int zb = r2 - yb * NBZ;

    int x0b = xb << 2, y0b = yb << 2, z0b = zb << 5;

    // ---- stage flow: 16 rows x (32 z * 3) floats = 24 f32x4 per row = 384 ----
    {
        int rr = tid / 24, q = tid - rr * 24;
        int xr = x0b + (rr >> 2), yr = y0b + (rr & 3);
        const f32x4* src = (const f32x4*)(flow +
            ((size_t)((bb * DIM + xr) * DIM + yr) * DIM + z0b) * 3);
        f32x4 v = __builtin_nontemporal_load(&src[q]);
        *(f32x4*)&sflow[rr * FROW + q * 4] = v;
    }
    if (tid < 128) {
        int i  = tid + 256;
        int rr = i / 24, q = i - rr * 24;
        int xr = x0b + (rr >> 2), yr = y0b + (rr & 3);
        const f32x4* src = (const f32x4*)(flow +
            ((size_t)((bb * DIM + xr) * DIM + yr) * DIM + z0b) * 3);
        f32x4 v = __builtin_nontemporal_load(&src[q]);
        *(f32x4*)&sflow[rr * FROW + q * 4] = v;
    }
    __syncthreads();

    // ---- thread -> 2 voxels: (row, lzA) and (row, lzA+16); wave = 4x4x4 cube per half
    int lx  = (tid >> 4) & 3;
    int ly  = (tid >> 2) & 3;
    int lzA = ((tid >> 6) << 2) | (tid & 3);   // 0..15
    int row = (lx << 2) | ly;

    int x = x0b + lx, y = y0b + ly;
    const float* vb = vol + (size_t)bb * DDD;
    const float maxf = (float)(DIM - 1);

    // phase 1: per-voxel weights + addresses, issue all 8 gathers
    float wx0[2], wx1[2], wy0[2], wy1[2], wz0[2], wz1[2];
    f32x2u p00[2], p10[2], p01[2], p11[2];
#pragma unroll
    for (int h = 0; h < 2; ++h) {
        int lz = lzA + h * 16;
        float fx = sflow[row * FROW + lz * 3 + 0];
        float fy = sflow[row * FROW + lz * 3 + 1];
        float fz = sflow[row * FROW + lz * 3 + 2];

        float lxf = fminf(fmaxf((float)x + fx, 0.0f), maxf);
        float lyf = fminf(fmaxf((float)y + fy, 0.0f), maxf);
        float lzf = fminf(fmaxf((float)(z0b + lz) + fz, 0.0f), maxf);

        // trunc == floor (nonneg); clipped value -> already in [0,159]
        int x0 = (int)lxf;
        int y0 = (int)lyf;
        int z0 = (int)lzf;
        int x1 = min(x0 + 1, DIM - 1);
        int y1 = min(y0 + 1, DIM - 1);
        int z1 = min(z0 + 1, DIM - 1);

        wx0[h] = (float)x1 - lxf;  wx1[h] = 1.0f - wx0[h];
        wy0[h] = (float)y1 - lyf;  wy1[h] = 1.0f - wy0[h];
        wz0[h] = (float)z1 - lzf;  wz1[h] = 1.0f - wz0[h];

        // delta-based corner addresses; zp=min(z0,158): at z0==159 wz0==0
        // exactly, so the stale low element contributes exactly 0.
        int zp  = min(z0, DIM - 2);
        int a00 = x0 * DD + y0 * DIM + zp;
        int dx  = (x1 - x0) * DD;
        int dy  = (y1 - y0) * DIM;
        p00[h] = *(const f32x2u*)(vb + a00);
        p10[h] = *(const f32x2u*)(vb + a00 + dx);
        p01[h] = *(const f32x2u*)(vb + a00 + dy);
        p11[h] = *(const f32x2u*)(vb + a00 + dx + dy);
    }

    // phase 2: factored FMA interpolation tree (z, then y, then x)
#pragma unroll
    for (int h = 0; h < 2; ++h) {
        float t00 = fmaf(wz1[h], p00[h].y, wz0[h] * p00[h].x);
        float t10 = fmaf(wz1[h], p10[h].y, wz0[h] * p10[h].x);
        float t01 = fmaf(wz1[h], p01[h].y, wz0[h] * p01[h].x);
        float t11 = fmaf(wz1[h], p11[h].y, wz0[h] * p11[h].x);
        float s0  = fmaf(wy1[h], t01, wy0[h] * t00);
        float s1  = fmaf(wy1[h], t11, wy0[h] * t10);
        float acc = fmaf(wx1[h], s1, wx0[h] * s0);
        sout[row * SOROW + lzA + h * 16] = acc;
    }
    __syncthreads();

    // ---- coalesced out: 16 rows x 16 f32x2 = 128B z-segments per row ----
    int ro = tid >> 4;     // row 0..15
    int j  = tid & 15;     // f32x2 position
    f32x2 v2 = *(const f32x2*)&sout[ro * SOROW + 2 * j];
    int xs = x0b + (ro >> 2);
    int ys = y0b + (ro & 3);
    __builtin_nontemporal_store(v2,
        (f32x2*)&out[(size_t)((bb * DIM + xs) * DIM + ys) * DIM + z0b + 2 * j]);
}

extern "C" void kernel_launch(void* const* d_in, const int* in_sizes, int n_in,
                              void* d_out, int out_size, void* d_ws, size_t ws_size,
                              hipStream_t stream)
{
    const float* vol  = (const float*)d_in[0];
    const float* flow = (const float*)d_in[1];
    float* out = (float*)d_out;

    st_warp_kernel<<<NBLK, BLK, 0, stream>>>(vol, flow, out);
}

// Round 17
// 194.057 us; speedup vs baseline: 1.1693x; 1.0130x over previous
//
#include <hip/hip_runtime.h>

// SpatialTransformer: trilinear warp of vol [B,X,Y,Z,1] by dense flow [B,X,Y,Z,3].
// B=2, X=Y=Z=160, fp32.
//
// Round-12 vs round-11 (61.6 us, VALU 24%, nothing saturated -> latency):
//  - 4 voxels per thread (tile 8x4x32, groups = {lx,lx+4} x {lz,lz+16}):
//    16 independent 8B gathers in flight per thread (was 8). Per-gather
//    wave footprint unchanged (each group is still a 4x4x4 cube), so L1
//    transactions/gather constant while memory-level parallelism doubles.
//  - flow staging (32 rows x 24 f32x4) and out staging (32 rows x 16 f32x2)
//    amortized over 1024 voxels/block.
//  - keeps: z-pair 8B gathers, VALU-trimmed addressing + factored FMA tree,
//    bijective XCD chunk swizzle, nontemporal flow/out.

typedef float f32x4 __attribute__((ext_vector_type(4)));
typedef float f32x2u __attribute__((ext_vector_type(2), aligned(4)));  // vol pairs (4B-aligned)
typedef float f32x2 __attribute__((ext_vector_type(2)));               // 8B-aligned

#define DIM 160
#define DD  (DIM * DIM)
#define DDD (DIM * DIM * DIM)
#define BLK 256
#define NBX 20
#define NBY 40
#define NBZ 5
#define TPB (NBX * NBY * NBZ)     // 4000 tiles per batch
#define NBLK (2 * TPB)            // 8000, divisible by 8
#define CHUNK (NBLK / 8)          // 1000

#define FROW 100   // 96 data + 4 pad: bank stride 4 -> worst 2-way (free)
#define SOROW 34

__global__ __launch_bounds__(256) void st_warp_kernel(
    const float* __restrict__ vol,
    const float* __restrict__ flow,
    float* __restrict__ out)
{
    __shared__ float sflow[32 * FROW];   // 12.8 KiB
    __shared__ float sout[32 * SOROW];   // 4.35 KiB

    int tid = threadIdx.x;
    int bid = blockIdx.x;
    // bijective XCD swizzle: XCD k gets contiguous chunk [k*CHUNK,(k+1)*CHUNK)
    int swz = (bid & 7) * CHUNK + (bid >> 3);

    // decode tile id: zb fastest
    int bb = swz / TPB;
    int r  = swz - bb * TPB;
    int xb = r / (NBY * NBZ);
    int r2 = r - xb * (NBY * NBZ);
    int yb = r2 / NBZ;
    int zb = r2 - yb * NBZ;

    int x0b = xb << 3, y0b = yb << 2, z0b = zb << 5;

    // ---- stage flow: 32 rows x (32 z * 3) floats = 24 f32x4 per row = 768 ----
#pragma unroll
    for (int k = 0; k < 3; ++k) {
        int i  = tid + k * 256;
        int rr = i / 24, q = i - rr * 24;        // row 0..31, float4 0..23
        int xr = x0b + (rr >> 2), yr = y0b + (rr & 3);
        const f32x4* src = (const f32x4*)(flow +
            ((size_t)((bb * DIM + xr) * DIM + yr) * DIM + z0b) * 3);
        f32x4 v = __builtin_nontemporal_load(&src[q]);
        *(f32x4*)&sflow[rr * FROW + q * 4] = v;
    }
    __syncthreads();

    // ---- thread -> 4 voxels: (lxA+4hx, ly, lzA+16hz); each group's wave
    //      footprint is a 4x4x4 cube (same as round-11) ----
    int lxA = (tid >> 4) & 3;
    int ly  = (tid >> 2) & 3;
    int lzA = ((tid >> 6) << 2) | (tid & 3);   // 0..15

    const float* vb = vol + (size_t)bb * DDD;
    const float maxf = (float)(DIM - 1);

    // phase 1: weights + addresses, issue all 16 gathers
    float wx0[4], wx1[4], wy0[4], wy1[4], wz0[4], wz1[4];
    f32x2u p00[4], p10[4], p01[4], p11[4];
#pragma unroll
    for (int g = 0; g < 4; ++g) {
        int hx = g & 1, hz = g >> 1;
        int lx = lxA + (hx << 2);
        int lz = lzA + (hz << 4);
        int row = (lx << 2) | ly;

        float fx = sflow[row * FROW + lz * 3 + 0];
        float fy = sflow[row * FROW + lz * 3 + 1];
        float fz = sflow[row * FROW + lz * 3 + 2];

        float lxf = fminf(fmaxf((float)(x0b + lx) + fx, 0.0f), maxf);
        float lyf = fminf(fmaxf((float)(y0b + ly) + fy, 0.0f), maxf);
        float lzf = fminf(fmaxf((float)(z0b + lz) + fz, 0.0f), maxf);

        // trunc == floor (nonneg); clipped -> already in [0,159]
        int x0 = (int)lxf;
        int y0 = (int)lyf;
        int z0 = (int)lzf;
        int x1 = min(x0 + 1, DIM - 1);
        int y1 = min(y0 + 1, DIM - 1);
        int z1 = min(z0 + 1, DIM - 1);

        wx0[g] = (float)x1 - lxf;  wx1[g] = 1.0f - wx0[g];
        wy0[g] = (float)y1 - lyf;  wy1[g] = 1.0f - wy0[g];
        wz0[g] = (float)z1 - lzf;  wz1[g] = 1.0f - wz0[g];

        // delta-based corner addresses; zp=min(z0,158): at z0==159 wz0==0
        // exactly, so the stale low element contributes exactly 0.
        int zp  = min(z0, DIM - 2);
        int a00 = x0 * DD + y0 * DIM + zp;
        int dx  = (x1 - x0) * DD;
        int dy  = (y1 - y0) * DIM;
        p00[g] = *(const f32x2u*)(vb + a00);
        p10[g] = *(const f32x2u*)(vb + a00 + dx);
        p01[g] = *(const f32x2u*)(vb + a00 + dy);
        p11[g] = *(const f32x2u*)(vb + a00 + dx + dy);
    }

    // phase 2: factored FMA interpolation tree (z, then y, then x)
#pragma unroll
    for (int g = 0; g < 4; ++g) {
        int hx = g & 1, hz = g >> 1;
        int lx = lxA + (hx << 2);
        int lz = lzA + (hz << 4);
        int row = (lx << 2) | ly;
        float t00 = fmaf(wz1[g], p00[g].y, wz0[g] * p00[g].x);
        float t10 = fmaf(wz1[g], p10[g].y, wz0[g] * p10[g].x);
        float t01 = fmaf(wz1[g], p01[g].y, wz0[g] * p01[g].x);
        float t11 = fmaf(wz1[g], p11[g].y, wz0[g] * p11[g].x);
        float s0  = fmaf(wy1[g], t01, wy0[g] * t00);
        float s1  = fmaf(wy1[g], t11, wy0[g] * t10);
        float acc = fmaf(wx1[g], s1, wx0[g] * s0);
        sout[row * SOROW + lz] = acc;
    }
    __syncthreads();

    // ---- coalesced out: 32 rows x 16 f32x2 = 128B z-segments, 2 per thread ----
#pragma unroll
    for (int k = 0; k < 2; ++k) {
        int i  = tid + k * 256;
        int ro = i >> 4;     // row 0..31
        int j  = i & 15;     // f32x2 position
        f32x2 v2 = *(const f32x2*)&sout[ro * SOROW + 2 * j];
        int xs = x0b + (ro >> 2);
        int ys = y0b + (ro & 3);
        __builtin_nontemporal_store(v2,
            (f32x2*)&out[(size_t)((bb * DIM + xs) * DIM + ys) * DIM + z0b + 2 * j]);
    }
}

extern "C" void kernel_launch(void* const* d_in, const int* in_sizes, int n_in,
                              void* d_out, int out_size, void* d_ws, size_t ws_size,
                              hipStream_t stream)
{
    const float* vol  = (const float*)d_in[0];
    const float* flow = (const float*)d_in[1];
    float* out = (float*)d_out;

    st_warp_kernel<<<NBLK, BLK, 0, stream>>>(vol, flow, out);
}